// Round 3
// baseline (1765.365 us; speedup 1.0000x reference)
//
#include <hip/hip_runtime.h>
#include <hip/hip_bf16.h>

typedef __bf16 bf16_t;
typedef bf16_t bf16x8 __attribute__((ext_vector_type(8)));
typedef float  f32x4  __attribute__((ext_vector_type(4)));

#define NN 100000
#define E1N 300000
#define E2N 150000
#define DD 256
#define BNEPS 1e-5f

// XOR swizzle (element index) for 64-col bf16 LDS tiles: kills the
// row-major stride-128B bank conflict on ds_read_b128 (guide §6 G4).
#define SWZ(row, col) ((col) ^ (((row) & 7) << 3))

// ---------------- param folding (fp32 in -> folded bf16/f32 out) ----------------
__global__ void prep_scalars(const float* b1a, const float* g1, const float* be1,
                             const float* m1, const float* v1,
                             const float* b1b, const float* gbrel,
                             const float* a1p, const float* a2p,
                             const float* g2, const float* be2,
                             const float* m2, const float* v2,
                             float* fold1, float* c2, float* s2f) {
  int c = threadIdx.x;
  float s1 = g1[c] * rsqrtf(v1[c] + BNEPS);
  fold1[c] = (b1a[c] - m1[c]) * s1 + be1[c];
  float s2 = g2[c] * rsqrtf(v2[c] + BNEPS);
  float cst = a1p[0] * b1b[c] + a2p[0] * gbrel[c];
  c2[c] = (cst - m2[c]) * s2 + be2[c];
  s2f[c] = s2;
}

__global__ void prep_w1(const float* w1a, const float* g1, const float* v1,
                        bf16_t* w1ab) {
  int o = blockIdx.x, i = threadIdx.x;
  float s1 = g1[o] * rsqrtf(v1[o] + BNEPS);
  w1ab[o * DD + i] = (bf16_t)(w1a[o * DD + i] * s1);
}

__global__ void prep_w2(const float* w1b, const float* wrel, const float* wroot,
                        const float* a1p, const float* a2p,
                        const float* g2, const float* v2, bf16_t* w2f) {
  int o = blockIdx.x, i = threadIdx.x;
  float s2 = g2[o] * rsqrtf(v2[o] + BNEPS);
  float a1 = a1p[0], a2 = a2p[0];
  w2f[o * 768 + i]       = (bf16_t)(w1b[o * DD + i]   * a1 * s2);
  w2f[o * 768 + 256 + i] = (bf16_t)(wrel[o * DD + i]  * a2 * s2);
  w2f[o * 768 + 512 + i] = (bf16_t)(wroot[o * DD + i] * a2 * s2);
}

// ---------------- aggregation buffers ----------------
// aggr1 starts at (1+eps)*x so the GINE scatter accumulates straight into
// the GEMM1 input; aggr2 starts at 0.
__global__ void init_aggr(const float* __restrict__ x, const float* epsp,
                          float* __restrict__ aggr1, float* __restrict__ aggr2) {
  int i = (blockIdx.x * 256 + threadIdx.x) * 4;
  float sc = 1.0f + epsp[0];
  f32x4 xv = *(const f32x4*)(x + i);
  f32x4 a;
#pragma unroll
  for (int j = 0; j < 4; ++j) a[j] = xv[j] * sc;
  f32x4 z = {0.f, 0.f, 0.f, 0.f};
  *(f32x4*)(aggr1 + i) = a;
  *(f32x4*)(aggr2 + i) = z;
}

// one wave per edge; lane covers 4 dims. ReLU lets us skip non-positive adds.
__global__ void scatter_gine(const float* __restrict__ x, const int* __restrict__ ei,
                             const float* __restrict__ eattr, float* __restrict__ aggr1) {
  int e = blockIdx.x * 4 + (threadIdx.x >> 6);
  if (e >= E1N) return;
  int lane = threadIdx.x & 63;
  int src = ei[e], dst = ei[E1N + e];
  int col = lane * 4;
  f32x4 xv = *(const f32x4*)(x + src * DD + col);
  f32x4 ev = *(const f32x4*)(eattr + e * DD + col);
  float* o = aggr1 + dst * DD + col;
#pragma unroll
  for (int j = 0; j < 4; ++j) {
    float m = xv[j] + ev[j];
    if (m > 0.f) unsafeAtomicAdd(o + j, m);
  }
}

__global__ void scatter_gc(const float* __restrict__ x, const int* __restrict__ vi,
                           float* __restrict__ aggr2) {
  int e = blockIdx.x * 4 + (threadIdx.x >> 6);
  if (e >= E2N) return;
  int lane = threadIdx.x & 63;
  int src = vi[e], dst = vi[E2N + e];
  int col = lane * 4;
  f32x4 xv = *(const f32x4*)(x + src * DD + col);
  float* o = aggr2 + dst * DD + col;
#pragma unroll
  for (int j = 0; j < 4; ++j) unsafeAtomicAdd(o + j, xv[j]);
}

// ---------------- GEMM1: t1 = relu(A1 @ w1abT + fold1), K=256 ----------------
__global__ __launch_bounds__(256) void gemm1(const float* __restrict__ aggr1,
                                             const bf16_t* __restrict__ w1ab,
                                             const float* __restrict__ fold1,
                                             bf16_t* __restrict__ t1) {
  __shared__ bf16_t As[128][64];
  __shared__ bf16_t Bs[128][64];
  const int tid = threadIdx.x;
  const int m0 = blockIdx.x * 128;
  const int n0 = blockIdx.y * 128;
  const int lane = tid & 63, wid = tid >> 6;
  const int wr = wid >> 1, wc = wid & 1;
  const int lr = lane & 15, kg = (lane >> 4) * 8;
  const int tcol = (tid & 7) * 8, trow = tid >> 3;

  f32x4 acc[4][4] = {};

  for (int kt = 0; kt < 4; ++kt) {
    const int k0 = kt * 64;
#pragma unroll
    for (int i = 0; i < 4; ++i) {
      int row = trow + i * 32;
      int gr = m0 + row; gr = gr < NN ? gr : NN - 1;
      const float* p = aggr1 + gr * DD + k0 + tcol;
      f32x4 v0 = *(const f32x4*)p;
      f32x4 v1 = *(const f32x4*)(p + 4);
      bf16x8 bv;
#pragma unroll
      for (int j = 0; j < 4; ++j) { bv[j] = (bf16_t)v0[j]; bv[4 + j] = (bf16_t)v1[j]; }
      *(bf16x8*)&As[row][SWZ(row, tcol)] = bv;
    }
#pragma unroll
    for (int i = 0; i < 4; ++i) {
      int row = trow + i * 32;
      *(bf16x8*)&Bs[row][SWZ(row, tcol)] =
          *(const bf16x8*)(w1ab + (n0 + row) * DD + k0 + tcol);
    }
    __syncthreads();
#pragma unroll
    for (int kk = 0; kk < 2; ++kk) {
      bf16x8 af[4], bfr[4];
#pragma unroll
      for (int m = 0; m < 4; ++m) {
        int r = wr * 64 + m * 16 + lr;
        af[m] = *(const bf16x8*)&As[r][SWZ(r, kk * 32 + kg)];
      }
#pragma unroll
      for (int n = 0; n < 4; ++n) {
        int r = wc * 64 + n * 16 + lr;
        bfr[n] = *(const bf16x8*)&Bs[r][SWZ(r, kk * 32 + kg)];
      }
#pragma unroll
      for (int m = 0; m < 4; ++m)
#pragma unroll
        for (int n = 0; n < 4; ++n)
          acc[m][n] = __builtin_amdgcn_mfma_f32_16x16x32_bf16(af[m], bfr[n], acc[m][n], 0, 0, 0);
    }
    __syncthreads();
  }

  const int rg = lane >> 4;
#pragma unroll
  for (int n = 0; n < 4; ++n) {
    int gc = n0 + wc * 64 + n * 16 + lr;
    float fo = fold1[gc];
#pragma unroll
    for (int m = 0; m < 4; ++m) {
      int gr0 = m0 + wr * 64 + m * 16 + rg * 4;
#pragma unroll
      for (int r = 0; r < 4; ++r) {
        int gr = gr0 + r;
        if (gr < NN) {
          float v = acc[m][n][r] + fo;
          t1[gr * DD + gc] = (bf16_t)(v > 0.f ? v : 0.f);
        }
      }
    }
  }
}

// ------- GEMM2: out = relu(x*s2 + [t1|aggr2|x] @ w2fT + c2), K=768 -------
// Output is FLOAT32 (reference output dtype).
__global__ __launch_bounds__(256) void gemm2(const bf16_t* __restrict__ t1,
                                             const float* __restrict__ aggr2,
                                             const float* __restrict__ x,
                                             const bf16_t* __restrict__ w2f,
                                             const float* __restrict__ c2,
                                             const float* __restrict__ s2f,
                                             float* __restrict__ out) {
  __shared__ bf16_t As[128][64];
  __shared__ bf16_t Bs[128][64];
  const int tid = threadIdx.x;
  const int m0 = blockIdx.x * 128;
  const int n0 = blockIdx.y * 128;
  const int lane = tid & 63, wid = tid >> 6;
  const int wr = wid >> 1, wc = wid & 1;
  const int lr = lane & 15, kg = (lane >> 4) * 8;
  const int tcol = (tid & 7) * 8, trow = tid >> 3;

  f32x4 acc[4][4] = {};

  for (int kt = 0; kt < 12; ++kt) {
#pragma unroll
    for (int i = 0; i < 4; ++i) {
      int row = trow + i * 32;
      int gr = m0 + row; gr = gr < NN ? gr : NN - 1;
      int kc = (kt & 3) * 64 + tcol;
      bf16x8 bv;
      if (kt < 4) {
        bv = *(const bf16x8*)(t1 + gr * DD + kc);
      } else {
        const float* p = (kt < 8 ? aggr2 : x) + gr * DD + kc;
        f32x4 v0 = *(const f32x4*)p;
        f32x4 v1 = *(const f32x4*)(p + 4);
#pragma unroll
        for (int j = 0; j < 4; ++j) { bv[j] = (bf16_t)v0[j]; bv[4 + j] = (bf16_t)v1[j]; }
      }
      *(bf16x8*)&As[row][SWZ(row, tcol)] = bv;
    }
#pragma unroll
    for (int i = 0; i < 4; ++i) {
      int row = trow + i * 32;
      *(bf16x8*)&Bs[row][SWZ(row, tcol)] =
          *(const bf16x8*)(w2f + (n0 + row) * 768 + kt * 64 + tcol);
    }
    __syncthreads();
#pragma unroll
    for (int kk = 0; kk < 2; ++kk) {
      bf16x8 af[4], bfr[4];
#pragma unroll
      for (int m = 0; m < 4; ++m) {
        int r = wr * 64 + m * 16 + lr;
        af[m] = *(const bf16x8*)&As[r][SWZ(r, kk * 32 + kg)];
      }
#pragma unroll
      for (int n = 0; n < 4; ++n) {
        int r = wc * 64 + n * 16 + lr;
        bfr[n] = *(const bf16x8*)&Bs[r][SWZ(r, kk * 32 + kg)];
      }
#pragma unroll
      for (int m = 0; m < 4; ++m)
#pragma unroll
        for (int n = 0; n < 4; ++n)
          acc[m][n] = __builtin_amdgcn_mfma_f32_16x16x32_bf16(af[m], bfr[n], acc[m][n], 0, 0, 0);
    }
    __syncthreads();
  }

  const int rg = lane >> 4;
#pragma unroll
  for (int n = 0; n < 4; ++n) {
    int gc = n0 + wc * 64 + n * 16 + lr;
    float c2v = c2[gc];
    float s2v = s2f[gc];
#pragma unroll
    for (int m = 0; m < 4; ++m) {
      int gr0 = m0 + wr * 64 + m * 16 + rg * 4;
#pragma unroll
      for (int r = 0; r < 4; ++r) {
        int gr = gr0 + r;
        if (gr < NN) {
          float v = acc[m][n][r] + c2v + x[gr * DD + gc] * s2v;
          out[gr * DD + gc] = (v > 0.f ? v : 0.f);
        }
      }
    }
  }
}

extern "C" void kernel_launch(void* const* d_in, const int* in_sizes, int n_in,
                              void* d_out, int out_size, void* d_ws, size_t ws_size,
                              hipStream_t stream) {
  const float* x     = (const float*)d_in[0];
  const int*   ei    = (const int*)d_in[1];
  const float* eattr = (const float*)d_in[2];
  const int*   vi    = (const int*)d_in[3];
  const float* epsp  = (const float*)d_in[4];
  const float* w1a   = (const float*)d_in[5];
  const float* b1a   = (const float*)d_in[6];
  const float* bn1g  = (const float*)d_in[7];
  const float* bn1b  = (const float*)d_in[8];
  const float* bn1m  = (const float*)d_in[9];
  const float* bn1v  = (const float*)d_in[10];
  const float* w1b   = (const float*)d_in[11];
  const float* b1b   = (const float*)d_in[12];
  const float* wrel  = (const float*)d_in[13];
  const float* gbrel = (const float*)d_in[14];
  const float* wroot = (const float*)d_in[15];
  const float* a1p   = (const float*)d_in[16];
  const float* a2p   = (const float*)d_in[17];
  const float* bng   = (const float*)d_in[18];
  const float* bnb   = (const float*)d_in[19];
  const float* bnm   = (const float*)d_in[20];
  const float* bnv   = (const float*)d_in[21];

  char* ws = (char*)d_ws;
  float*  aggr1 = (float*)ws;                      // 102,400,000 B
  float*  aggr2 = (float*)(ws + 102400000);        // 102,400,000 B
  bf16_t* t1    = (bf16_t*)(ws + 204800000);       //  51,200,000 B
  bf16_t* w1ab  = (bf16_t*)(ws + 256000000);       //     131,072 B
  bf16_t* w2f   = (bf16_t*)(ws + 256131072);       //     393,216 B
  float*  fold1 = (float*)(ws + 256524288);        //       1,024 B
  float*  c2    = (float*)(ws + 256525312);        //       1,024 B
  float*  s2f   = (float*)(ws + 256526336);        //       1,024 B
  // total ws use: 256,527,360 B

  prep_scalars<<<1, 256, 0, stream>>>(b1a, bn1g, bn1b, bn1m, bn1v, b1b, gbrel,
                                      a1p, a2p, bng, bnb, bnm, bnv, fold1, c2, s2f);
  prep_w1<<<256, 256, 0, stream>>>(w1a, bn1g, bn1v, w1ab);
  prep_w2<<<256, 256, 0, stream>>>(w1b, wrel, wroot, a1p, a2p, bng, bnv, w2f);
  init_aggr<<<25000, 256, 0, stream>>>(x, epsp, aggr1, aggr2);
  scatter_gine<<<75000, 256, 0, stream>>>(x, ei, eattr, aggr1);
  scatter_gc<<<37500, 256, 0, stream>>>(x, vi, aggr2);
  gemm1<<<dim3(782, 2), 256, 0, stream>>>(aggr1, w1ab, fold1, t1);
  gemm2<<<dim3(782, 2), 256, 0, stream>>>(t1, aggr2, x, w2f, c2, s2f, (float*)d_out);
}

// Round 4
// 462.625 us; speedup vs baseline: 3.8160x; 3.8160x over previous
//
#include <hip/hip_runtime.h>
#include <hip/hip_bf16.h>

typedef __bf16 bf16_t;
typedef bf16_t bf16x8 __attribute__((ext_vector_type(8)));
typedef bf16_t bf16x4 __attribute__((ext_vector_type(4)));
typedef float  f32x4  __attribute__((ext_vector_type(4)));

#define NN 100000
#define E1N 300000
#define E2N 150000
#define DD 256
#define BNEPS 1e-5f

// XOR swizzle (element index) for 64-col bf16 LDS tiles: kills the
// row-major stride-128B bank conflict on ds_read_b128 (guide §6 G4).
#define SWZ(row, col) ((col) ^ (((row) & 7) << 3))

// ---------------- param folding (fp32 in -> folded bf16/f32 out) ----------------
__global__ void prep_scalars(const float* b1a, const float* g1, const float* be1,
                             const float* m1, const float* v1,
                             const float* b1b, const float* gbrel,
                             const float* a1p, const float* a2p,
                             const float* g2, const float* be2,
                             const float* m2, const float* v2,
                             float* fold1, float* c2, float* s2f) {
  int c = threadIdx.x;
  float s1 = g1[c] * rsqrtf(v1[c] + BNEPS);
  fold1[c] = (b1a[c] - m1[c]) * s1 + be1[c];
  float s2 = g2[c] * rsqrtf(v2[c] + BNEPS);
  float cst = a1p[0] * b1b[c] + a2p[0] * gbrel[c];
  c2[c] = (cst - m2[c]) * s2 + be2[c];
  s2f[c] = s2;
}

__global__ void prep_w1(const float* w1a, const float* g1, const float* v1,
                        bf16_t* w1ab) {
  int o = blockIdx.x, i = threadIdx.x;
  float s1 = g1[o] * rsqrtf(v1[o] + BNEPS);
  w1ab[o * DD + i] = (bf16_t)(w1a[o * DD + i] * s1);
}

__global__ void prep_w2(const float* w1b, const float* wrel, const float* wroot,
                        const float* a1p, const float* a2p,
                        const float* g2, const float* v2, bf16_t* w2f) {
  int o = blockIdx.x, i = threadIdx.x;
  float s2 = g2[o] * rsqrtf(v2[o] + BNEPS);
  float a1 = a1p[0], a2 = a2p[0];
  w2f[o * 768 + i]       = (bf16_t)(w1b[o * DD + i]   * a1 * s2);
  w2f[o * 768 + 256 + i] = (bf16_t)(wrel[o * DD + i]  * a2 * s2);
  w2f[o * 768 + 512 + i] = (bf16_t)(wroot[o * DD + i] * a2 * s2);
}

// ---------------- per-node edge lists (replaces fp32 atomic scatter) ----------------
__global__ void init_heads(int* head1, int* head2) {
  int i = blockIdx.x * 256 + threadIdx.x;
  if (i < NN) { head1[i] = -1; head2[i] = -1; }
}

__global__ void build_lists(const int* __restrict__ ei, const int* __restrict__ vi,
                            int* head1, int* next1, int* head2, int* next2) {
  int e = blockIdx.x * 256 + threadIdx.x;
  if (e < E1N) {
    int dst = ei[E1N + e];
    next1[e] = atomicExch(head1 + dst, e);
  }
  if (e < E2N) {
    int dst = vi[E2N + e];
    next2[e] = atomicExch(head2 + dst, e);
  }
}

// One wave per node: walk both edge lists, accumulate in registers, write
// aggr1 = (1+eps)x + sum relu(x[src]+eattr), aggr2 = sum x[src], and x cast
// to bf16 — all atomic-free, all outputs pre-cast to bf16 for the GEMMs.
__global__ __launch_bounds__(256) void aggregate(
    const float* __restrict__ x, const float* epsp,
    const int* __restrict__ ei, const float* __restrict__ eattr,
    const int* __restrict__ vi,
    const int* __restrict__ head1, const int* __restrict__ next1,
    const int* __restrict__ head2, const int* __restrict__ next2,
    bf16_t* __restrict__ aggr1_bf, bf16_t* __restrict__ aggr2_bf,
    bf16_t* __restrict__ xbf) {
  int n = blockIdx.x * 4 + (threadIdx.x >> 6);
  int lane = threadIdx.x & 63;
  int col = lane * 4;
  float sc = 1.0f + epsp[0];
  f32x4 xv = *(const f32x4*)(x + (size_t)n * DD + col);
  f32x4 acc1, acc2 = {0.f, 0.f, 0.f, 0.f};
#pragma unroll
  for (int j = 0; j < 4; ++j) acc1[j] = xv[j] * sc;

  for (int e = head1[n]; e >= 0; e = next1[e]) {
    int src = ei[e];
    f32x4 a = *(const f32x4*)(x + (size_t)src * DD + col);
    f32x4 b = *(const f32x4*)(eattr + (size_t)e * DD + col);
#pragma unroll
    for (int j = 0; j < 4; ++j) {
      float m = a[j] + b[j];
      acc1[j] += (m > 0.f ? m : 0.f);
    }
  }
  for (int e = head2[n]; e >= 0; e = next2[e]) {
    int src = vi[e];
    f32x4 a = *(const f32x4*)(x + (size_t)src * DD + col);
#pragma unroll
    for (int j = 0; j < 4; ++j) acc2[j] += a[j];
  }

  bf16x4 o1, o2, o3;
#pragma unroll
  for (int j = 0; j < 4; ++j) {
    o1[j] = (bf16_t)acc1[j];
    o2[j] = (bf16_t)acc2[j];
    o3[j] = (bf16_t)xv[j];
  }
  *(bf16x4*)(aggr1_bf + (size_t)n * DD + col) = o1;
  *(bf16x4*)(aggr2_bf + (size_t)n * DD + col) = o2;
  *(bf16x4*)(xbf + (size_t)n * DD + col) = o3;
}

// ---------------- GEMM1: t1 = relu(aggr1 @ w1abT + fold1), K=256 ----------------
__global__ __launch_bounds__(256) void gemm1(const bf16_t* __restrict__ aggr1_bf,
                                             const bf16_t* __restrict__ w1ab,
                                             const float* __restrict__ fold1,
                                             bf16_t* __restrict__ t1) {
  __shared__ bf16_t As[128][64];
  __shared__ bf16_t Bs[128][64];
  const int tid = threadIdx.x;
  const int m0 = blockIdx.x * 128;
  const int n0 = blockIdx.y * 128;
  const int lane = tid & 63, wid = tid >> 6;
  const int wr = wid >> 1, wc = wid & 1;
  const int lr = lane & 15, kg = (lane >> 4) * 8;
  const int tcol = (tid & 7) * 8, trow = tid >> 3;

  f32x4 acc[4][4] = {};

  for (int kt = 0; kt < 4; ++kt) {
    const int k0 = kt * 64;
#pragma unroll
    for (int i = 0; i < 4; ++i) {
      int row = trow + i * 32;
      int gr = m0 + row; gr = gr < NN ? gr : NN - 1;
      *(bf16x8*)&As[row][SWZ(row, tcol)] =
          *(const bf16x8*)(aggr1_bf + (size_t)gr * DD + k0 + tcol);
    }
#pragma unroll
    for (int i = 0; i < 4; ++i) {
      int row = trow + i * 32;
      *(bf16x8*)&Bs[row][SWZ(row, tcol)] =
          *(const bf16x8*)(w1ab + (n0 + row) * DD + k0 + tcol);
    }
    __syncthreads();
#pragma unroll
    for (int kk = 0; kk < 2; ++kk) {
      bf16x8 af[4], bfr[4];
#pragma unroll
      for (int m = 0; m < 4; ++m) {
        int r = wr * 64 + m * 16 + lr;
        af[m] = *(const bf16x8*)&As[r][SWZ(r, kk * 32 + kg)];
      }
#pragma unroll
      for (int n = 0; n < 4; ++n) {
        int r = wc * 64 + n * 16 + lr;
        bfr[n] = *(const bf16x8*)&Bs[r][SWZ(r, kk * 32 + kg)];
      }
#pragma unroll
      for (int m = 0; m < 4; ++m)
#pragma unroll
        for (int n = 0; n < 4; ++n)
          acc[m][n] = __builtin_amdgcn_mfma_f32_16x16x32_bf16(af[m], bfr[n], acc[m][n], 0, 0, 0);
    }
    __syncthreads();
  }

  const int rg = lane >> 4;
#pragma unroll
  for (int n = 0; n < 4; ++n) {
    int gc = n0 + wc * 64 + n * 16 + lr;
    float fo = fold1[gc];
#pragma unroll
    for (int m = 0; m < 4; ++m) {
      int gr0 = m0 + wr * 64 + m * 16 + rg * 4;
#pragma unroll
      for (int r = 0; r < 4; ++r) {
        int gr = gr0 + r;
        if (gr < NN) {
          float v = acc[m][n][r] + fo;
          t1[(size_t)gr * DD + gc] = (bf16_t)(v > 0.f ? v : 0.f);
        }
      }
    }
  }
}

// ------- GEMM2: out = relu(x*s2 + [t1|aggr2|x] @ w2fT + c2), K=768, fp32 out -------
__global__ __launch_bounds__(256) void gemm2(const bf16_t* __restrict__ t1,
                                             const bf16_t* __restrict__ aggr2_bf,
                                             const bf16_t* __restrict__ xbf,
                                             const float* __restrict__ x,
                                             const bf16_t* __restrict__ w2f,
                                             const float* __restrict__ c2,
                                             const float* __restrict__ s2f,
                                             float* __restrict__ out) {
  __shared__ bf16_t As[128][64];
  __shared__ bf16_t Bs[128][64];
  const int tid = threadIdx.x;
  const int m0 = blockIdx.x * 128;
  const int n0 = blockIdx.y * 128;
  const int lane = tid & 63, wid = tid >> 6;
  const int wr = wid >> 1, wc = wid & 1;
  const int lr = lane & 15, kg = (lane >> 4) * 8;
  const int tcol = (tid & 7) * 8, trow = tid >> 3;

  f32x4 acc[4][4] = {};

  for (int kt = 0; kt < 12; ++kt) {
    const bf16_t* srcp = (kt < 4) ? t1 : (kt < 8 ? aggr2_bf : xbf);
    const int kc = (kt & 3) * 64 + tcol;
#pragma unroll
    for (int i = 0; i < 4; ++i) {
      int row = trow + i * 32;
      int gr = m0 + row; gr = gr < NN ? gr : NN - 1;
      *(bf16x8*)&As[row][SWZ(row, tcol)] =
          *(const bf16x8*)(srcp + (size_t)gr * DD + kc);
    }
#pragma unroll
    for (int i = 0; i < 4; ++i) {
      int row = trow + i * 32;
      *(bf16x8*)&Bs[row][SWZ(row, tcol)] =
          *(const bf16x8*)(w2f + (size_t)(n0 + row) * 768 + kt * 64 + tcol);
    }
    __syncthreads();
#pragma unroll
    for (int kk = 0; kk < 2; ++kk) {
      bf16x8 af[4], bfr[4];
#pragma unroll
      for (int m = 0; m < 4; ++m) {
        int r = wr * 64 + m * 16 + lr;
        af[m] = *(const bf16x8*)&As[r][SWZ(r, kk * 32 + kg)];
      }
#pragma unroll
      for (int n = 0; n < 4; ++n) {
        int r = wc * 64 + n * 16 + lr;
        bfr[n] = *(const bf16x8*)&Bs[r][SWZ(r, kk * 32 + kg)];
      }
#pragma unroll
      for (int m = 0; m < 4; ++m)
#pragma unroll
        for (int n = 0; n < 4; ++n)
          acc[m][n] = __builtin_amdgcn_mfma_f32_16x16x32_bf16(af[m], bfr[n], acc[m][n], 0, 0, 0);
    }
    __syncthreads();
  }

  const int rg = lane >> 4;
#pragma unroll
  for (int n = 0; n < 4; ++n) {
    int gc = n0 + wc * 64 + n * 16 + lr;
    float c2v = c2[gc];
    float s2v = s2f[gc];
#pragma unroll
    for (int m = 0; m < 4; ++m) {
      int gr0 = m0 + wr * 64 + m * 16 + rg * 4;
#pragma unroll
      for (int r = 0; r < 4; ++r) {
        int gr = gr0 + r;
        if (gr < NN) {
          float v = acc[m][n][r] + c2v + x[(size_t)gr * DD + gc] * s2v;
          out[(size_t)gr * DD + gc] = (v > 0.f ? v : 0.f);
        }
      }
    }
  }
}

extern "C" void kernel_launch(void* const* d_in, const int* in_sizes, int n_in,
                              void* d_out, int out_size, void* d_ws, size_t ws_size,
                              hipStream_t stream) {
  const float* x     = (const float*)d_in[0];
  const int*   ei    = (const int*)d_in[1];
  const float* eattr = (const float*)d_in[2];
  const int*   vi    = (const int*)d_in[3];
  const float* epsp  = (const float*)d_in[4];
  const float* w1a   = (const float*)d_in[5];
  const float* b1a   = (const float*)d_in[6];
  const float* bn1g  = (const float*)d_in[7];
  const float* bn1b  = (const float*)d_in[8];
  const float* bn1m  = (const float*)d_in[9];
  const float* bn1v  = (const float*)d_in[10];
  const float* w1b   = (const float*)d_in[11];
  const float* b1b   = (const float*)d_in[12];
  const float* wrel  = (const float*)d_in[13];
  const float* gbrel = (const float*)d_in[14];
  const float* wroot = (const float*)d_in[15];
  const float* a1p   = (const float*)d_in[16];
  const float* a2p   = (const float*)d_in[17];
  const float* bng   = (const float*)d_in[18];
  const float* bnb   = (const float*)d_in[19];
  const float* bnm   = (const float*)d_in[20];
  const float* bnv   = (const float*)d_in[21];

  char* ws = (char*)d_ws;
  bf16_t* aggr1_bf = (bf16_t*)ws;                    //  51,200,000 B
  bf16_t* aggr2_bf = (bf16_t*)(ws + 51200000);       //  51,200,000 B
  bf16_t* xbf      = (bf16_t*)(ws + 102400000);      //  51,200,000 B
  bf16_t* t1       = (bf16_t*)(ws + 153600000);      //  51,200,000 B
  bf16_t* w1ab     = (bf16_t*)(ws + 204800000);      //     131,072 B
  bf16_t* w2f      = (bf16_t*)(ws + 204931072);      //     393,216 B
  float*  fold1    = (float*)(ws + 205324288);       //       1,024 B
  float*  c2       = (float*)(ws + 205325312);       //       1,024 B
  float*  s2f      = (float*)(ws + 205326336);       //       1,024 B
  int*    head1    = (int*)(ws + 205327360);         //     400,000 B
  int*    head2    = (int*)(ws + 205727360);         //     400,000 B
  int*    next1    = (int*)(ws + 206127360);         //   1,200,000 B
  int*    next2    = (int*)(ws + 207327360);         //     600,000 B
  // total ws use: 207,927,360 B

  prep_scalars<<<1, 256, 0, stream>>>(b1a, bn1g, bn1b, bn1m, bn1v, b1b, gbrel,
                                      a1p, a2p, bng, bnb, bnm, bnv, fold1, c2, s2f);
  prep_w1<<<256, 256, 0, stream>>>(w1a, bn1g, bn1v, w1ab);
  prep_w2<<<256, 256, 0, stream>>>(w1b, wrel, wroot, a1p, a2p, bng, bnv, w2f);
  init_heads<<<391, 256, 0, stream>>>(head1, head2);
  build_lists<<<1172, 256, 0, stream>>>(ei, vi, head1, next1, head2, next2);
  aggregate<<<25000, 256, 0, stream>>>(x, epsp, ei, eattr, vi,
                                       head1, next1, head2, next2,
                                       aggr1_bf, aggr2_bf, xbf);
  gemm1<<<dim3(782, 2), 256, 0, stream>>>(aggr1_bf, w1ab, fold1, t1);
  gemm2<<<dim3(782, 2), 256, 0, stream>>>(t1, aggr2_bf, xbf, x, w2f, c2, s2f,
                                          (float*)d_out);
}

// Round 5
// 344.752 us; speedup vs baseline: 5.1207x; 1.3419x over previous
//
#include <hip/hip_runtime.h>
#include <hip/hip_bf16.h>

typedef __bf16 bf16_t;
typedef bf16_t bf16x8 __attribute__((ext_vector_type(8)));
typedef bf16_t bf16x4 __attribute__((ext_vector_type(4)));
typedef float  f32x4  __attribute__((ext_vector_type(4)));

#define NN 100000
#define E1N 300000
#define E2N 150000
#define DD 256
#define BNEPS 1e-5f

// XOR swizzle (element index) within a 64-col bf16 LDS tile row.
#define SWZ(row, col) ((col) ^ (((row) & 7) << 3))

// global -> LDS direct (16B/lane). LDS dest is wave-uniform base + lane*16.
__device__ __forceinline__ void glds16(const bf16_t* src, bf16_t* ldsbase) {
  __builtin_amdgcn_global_load_lds(
      (const __attribute__((address_space(1))) void*)src,
      (__attribute__((address_space(3))) void*)ldsbase, 16, 0, 0);
}

// ---------------- param folding ----------------
__global__ void prep_scalars(const float* b1a, const float* g1, const float* be1,
                             const float* m1, const float* v1,
                             const float* b1b, const float* gbrel,
                             const float* a1p, const float* a2p,
                             const float* g2, const float* be2,
                             const float* m2, const float* v2,
                             float* fold1, float* c2, float* s2f) {
  int c = threadIdx.x;
  float s1 = g1[c] * rsqrtf(v1[c] + BNEPS);
  fold1[c] = (b1a[c] - m1[c]) * s1 + be1[c];
  float s2 = g2[c] * rsqrtf(v2[c] + BNEPS);
  float cst = a1p[0] * b1b[c] + a2p[0] * gbrel[c];
  c2[c] = (cst - m2[c]) * s2 + be2[c];
  s2f[c] = s2;
}

__global__ void prep_w1(const float* w1a, const float* g1, const float* v1,
                        bf16_t* w1ab) {
  int o = blockIdx.x, i = threadIdx.x;
  float s1 = g1[o] * rsqrtf(v1[o] + BNEPS);
  w1ab[o * DD + i] = (bf16_t)(w1a[o * DD + i] * s1);
}

__global__ void prep_w2(const float* w1b, const float* wrel, const float* wroot,
                        const float* a1p, const float* a2p,
                        const float* g2, const float* v2, bf16_t* w2f) {
  int o = blockIdx.x, i = threadIdx.x;
  float s2 = g2[o] * rsqrtf(v2[o] + BNEPS);
  float a1 = a1p[0], a2 = a2p[0];
  w2f[o * 768 + i]       = (bf16_t)(w1b[o * DD + i]   * a1 * s2);
  w2f[o * 768 + 256 + i] = (bf16_t)(wrel[o * DD + i]  * a2 * s2);
  w2f[o * 768 + 512 + i] = (bf16_t)(wroot[o * DD + i] * a2 * s2);
}

// ---------------- x -> bf16 pre-cast (halves gather bytes downstream) -------
__global__ void cast_x(const float* __restrict__ x, bf16_t* __restrict__ xbf) {
  size_t i = (size_t)(blockIdx.x * 256 + threadIdx.x) * 8;
  f32x4 v0 = *(const f32x4*)(x + i);
  f32x4 v1 = *(const f32x4*)(x + i + 4);
  bf16x8 o;
#pragma unroll
  for (int j = 0; j < 4; ++j) { o[j] = (bf16_t)v0[j]; o[4 + j] = (bf16_t)v1[j]; }
  *(bf16x8*)(xbf + i) = o;
}

// ---------------- per-node edge lists ----------------
__global__ void init_heads(int* head1, int* head2) {
  int i = blockIdx.x * 256 + threadIdx.x;
  if (i < NN) { head1[i] = -1; head2[i] = -1; }
}

__global__ void build_lists(const int* __restrict__ ei, const int* __restrict__ vi,
                            int* head1, int* next1, int* head2, int* next2) {
  int e = blockIdx.x * 256 + threadIdx.x;
  if (e < E1N) {
    int dst = ei[E1N + e];
    next1[e] = atomicExch(head1 + dst, e);
  }
  if (e < E2N) {
    int dst = vi[E2N + e];
    next2[e] = atomicExch(head2 + dst, e);
  }
}

// One wave per node: walk both lists, accumulate in registers, write bf16.
__global__ __launch_bounds__(256) void aggregate(
    const bf16_t* __restrict__ xbf, const float* epsp,
    const int* __restrict__ ei, const float* __restrict__ eattr,
    const int* __restrict__ vi,
    const int* __restrict__ head1, const int* __restrict__ next1,
    const int* __restrict__ head2, const int* __restrict__ next2,
    bf16_t* __restrict__ aggr1_bf, bf16_t* __restrict__ aggr2_bf) {
  int n = blockIdx.x * 4 + (threadIdx.x >> 6);
  int lane = threadIdx.x & 63;
  int col = lane * 4;
  float sc = 1.0f + epsp[0];
  bf16x4 xv = *(const bf16x4*)(xbf + (size_t)n * DD + col);
  f32x4 acc1, acc2 = {0.f, 0.f, 0.f, 0.f};
#pragma unroll
  for (int j = 0; j < 4; ++j) acc1[j] = (float)xv[j] * sc;

  for (int e = head1[n]; e >= 0; e = next1[e]) {
    int src = ei[e];
    bf16x4 a = *(const bf16x4*)(xbf + (size_t)src * DD + col);
    f32x4 b = *(const f32x4*)(eattr + (size_t)e * DD + col);
#pragma unroll
    for (int j = 0; j < 4; ++j) {
      float m = (float)a[j] + b[j];
      acc1[j] += (m > 0.f ? m : 0.f);
    }
  }
  for (int e = head2[n]; e >= 0; e = next2[e]) {
    int src = vi[e];
    bf16x4 a = *(const bf16x4*)(xbf + (size_t)src * DD + col);
#pragma unroll
    for (int j = 0; j < 4; ++j) acc2[j] += (float)a[j];
  }

  bf16x4 o1, o2;
#pragma unroll
  for (int j = 0; j < 4; ++j) { o1[j] = (bf16_t)acc1[j]; o2[j] = (bf16_t)acc2[j]; }
  *(bf16x4*)(aggr1_bf + (size_t)n * DD + col) = o1;
  *(bf16x4*)(aggr2_bf + (size_t)n * DD + col) = o2;
}

// ------- GEMM1: t1 = relu(aggr1 @ w1abT + fold1). 128x256 block, 8 waves -------
__global__ __launch_bounds__(512) void gemm1(const bf16_t* __restrict__ aggr1_bf,
                                             const bf16_t* __restrict__ w1ab,
                                             const float* __restrict__ fold1,
                                             bf16_t* __restrict__ t1) {
  __shared__ bf16_t As[128][64];
  __shared__ bf16_t Bs[256][64];
  const int tid = threadIdx.x;
  const int m0 = blockIdx.x * 128;
  const int lane = tid & 63, wid = tid >> 6;
  const int wr = wid >> 2, wc = wid & 3;          // wave -> 64x64 output tile
  const int lr = lane & 15, kg = (lane >> 4) * 8;
  const int lrow = lane >> 3;                      // row within 8-row chunk
  const int lcol = ((lane & 7) ^ (lane >> 3)) * 8; // pre-swizzled source col

  f32x4 acc[4][4] = {};

  for (int kt = 0; kt < 4; ++kt) {
    const int k0 = kt * 64;
#pragma unroll
    for (int i = 0; i < 2; ++i) {                  // A: wave stages 16 rows
      int r0 = wid * 16 + i * 8;
      glds16(aggr1_bf + (size_t)(m0 + r0 + lrow) * DD + k0 + lcol, &As[r0][0]);
    }
#pragma unroll
    for (int i = 0; i < 4; ++i) {                  // B: wave stages 32 rows
      int r0 = wid * 32 + i * 8;
      glds16(w1ab + (size_t)(r0 + lrow) * DD + k0 + lcol, &Bs[r0][0]);
    }
    __syncthreads();
#pragma unroll
    for (int kk = 0; kk < 2; ++kk) {
      bf16x8 af[4], bfr[4];
#pragma unroll
      for (int m = 0; m < 4; ++m) {
        int r = wr * 64 + m * 16 + lr;
        af[m] = *(const bf16x8*)&As[r][SWZ(r, kk * 32 + kg)];
      }
#pragma unroll
      for (int n = 0; n < 4; ++n) {
        int r = wc * 64 + n * 16 + lr;
        bfr[n] = *(const bf16x8*)&Bs[r][SWZ(r, kk * 32 + kg)];
      }
#pragma unroll
      for (int m = 0; m < 4; ++m)
#pragma unroll
        for (int n = 0; n < 4; ++n)
          acc[m][n] = __builtin_amdgcn_mfma_f32_16x16x32_bf16(af[m], bfr[n], acc[m][n], 0, 0, 0);
    }
    __syncthreads();
  }

  const int rg = lane >> 4;
#pragma unroll
  for (int n = 0; n < 4; ++n) {
    int gc = wc * 64 + n * 16 + lr;
    float fo = fold1[gc];
#pragma unroll
    for (int m = 0; m < 4; ++m) {
      int gr0 = m0 + wr * 64 + m * 16 + rg * 4;
#pragma unroll
      for (int r = 0; r < 4; ++r) {
        int gr = gr0 + r;
        if (gr < NN) {
          float v = acc[m][n][r] + fo;
          t1[(size_t)gr * DD + gc] = (bf16_t)(v > 0.f ? v : 0.f);
        }
      }
    }
  }
}

// --- GEMM2: out = relu(xbf*s2 + [t1|aggr2|xbf] @ w2fT + c2). 128x256 block ---
__global__ __launch_bounds__(512) void gemm2(const bf16_t* __restrict__ t1,
                                             const bf16_t* __restrict__ aggr2_bf,
                                             const bf16_t* __restrict__ xbf,
                                             const bf16_t* __restrict__ w2f,
                                             const float* __restrict__ c2,
                                             const float* __restrict__ s2f,
                                             float* __restrict__ out) {
  __shared__ bf16_t As[128][64];
  __shared__ bf16_t Bs[256][64];
  const int tid = threadIdx.x;
  const int m0 = blockIdx.x * 128;
  const int lane = tid & 63, wid = tid >> 6;
  const int wr = wid >> 2, wc = wid & 3;
  const int lr = lane & 15, kg = (lane >> 4) * 8;
  const int lrow = lane >> 3;
  const int lcol = ((lane & 7) ^ (lane >> 3)) * 8;

  f32x4 acc[4][4] = {};

  for (int kt = 0; kt < 12; ++kt) {
    const bf16_t* Asrc = (kt < 4) ? t1 : (kt < 8 ? aggr2_bf : xbf);
    const int k0 = (kt & 3) * 64;
#pragma unroll
    for (int i = 0; i < 2; ++i) {
      int r0 = wid * 16 + i * 8;
      glds16(Asrc + (size_t)(m0 + r0 + lrow) * DD + k0 + lcol, &As[r0][0]);
    }
#pragma unroll
    for (int i = 0; i < 4; ++i) {
      int r0 = wid * 32 + i * 8;
      glds16(w2f + (size_t)(r0 + lrow) * 768 + kt * 64 + lcol, &Bs[r0][0]);
    }
    __syncthreads();
#pragma unroll
    for (int kk = 0; kk < 2; ++kk) {
      bf16x8 af[4], bfr[4];
#pragma unroll
      for (int m = 0; m < 4; ++m) {
        int r = wr * 64 + m * 16 + lr;
        af[m] = *(const bf16x8*)&As[r][SWZ(r, kk * 32 + kg)];
      }
#pragma unroll
      for (int n = 0; n < 4; ++n) {
        int r = wc * 64 + n * 16 + lr;
        bfr[n] = *(const bf16x8*)&Bs[r][SWZ(r, kk * 32 + kg)];
      }
#pragma unroll
      for (int m = 0; m < 4; ++m)
#pragma unroll
        for (int n = 0; n < 4; ++n)
          acc[m][n] = __builtin_amdgcn_mfma_f32_16x16x32_bf16(af[m], bfr[n], acc[m][n], 0, 0, 0);
    }
    __syncthreads();
  }

  const int rg = lane >> 4;
#pragma unroll
  for (int n = 0; n < 4; ++n) {
    int gc = wc * 64 + n * 16 + lr;
    float c2v = c2[gc];
    float s2v = s2f[gc];
#pragma unroll
    for (int m = 0; m < 4; ++m) {
      int gr0 = m0 + wr * 64 + m * 16 + rg * 4;
#pragma unroll
      for (int r = 0; r < 4; ++r) {
        int gr = gr0 + r;
        if (gr < NN) {
          float v = acc[m][n][r] + c2v + (float)xbf[(size_t)gr * DD + gc] * s2v;
          out[(size_t)gr * DD + gc] = (v > 0.f ? v : 0.f);
        }
      }
    }
  }
}

extern "C" void kernel_launch(void* const* d_in, const int* in_sizes, int n_in,
                              void* d_out, int out_size, void* d_ws, size_t ws_size,
                              hipStream_t stream) {
  const float* x     = (const float*)d_in[0];
  const int*   ei    = (const int*)d_in[1];
  const float* eattr = (const float*)d_in[2];
  const int*   vi    = (const int*)d_in[3];
  const float* epsp  = (const float*)d_in[4];
  const float* w1a   = (const float*)d_in[5];
  const float* b1a   = (const float*)d_in[6];
  const float* bn1g  = (const float*)d_in[7];
  const float* bn1b  = (const float*)d_in[8];
  const float* bn1m  = (const float*)d_in[9];
  const float* bn1v  = (const float*)d_in[10];
  const float* w1b   = (const float*)d_in[11];
  const float* b1b   = (const float*)d_in[12];
  const float* wrel  = (const float*)d_in[13];
  const float* gbrel = (const float*)d_in[14];
  const float* wroot = (const float*)d_in[15];
  const float* a1p   = (const float*)d_in[16];
  const float* a2p   = (const float*)d_in[17];
  const float* bng   = (const float*)d_in[18];
  const float* bnb   = (const float*)d_in[19];
  const float* bnm   = (const float*)d_in[20];
  const float* bnv   = (const float*)d_in[21];

  char* ws = (char*)d_ws;
  bf16_t* aggr1_bf = (bf16_t*)ws;                    //  51,200,000 B
  bf16_t* aggr2_bf = (bf16_t*)(ws + 51200000);       //  51,200,000 B
  bf16_t* xbf      = (bf16_t*)(ws + 102400000);      //  51,200,000 B
  bf16_t* t1       = (bf16_t*)(ws + 153600000);      //  51,200,000 B
  bf16_t* w1ab     = (bf16_t*)(ws + 204800000);      //     131,072 B
  bf16_t* w2f      = (bf16_t*)(ws + 204931072);      //     393,216 B
  float*  fold1    = (float*)(ws + 205324288);       //       1,024 B
  float*  c2       = (float*)(ws + 205325312);       //       1,024 B
  float*  s2f      = (float*)(ws + 205326336);       //       1,024 B
  int*    head1    = (int*)(ws + 205327360);         //     400,000 B
  int*    head2    = (int*)(ws + 205727360);         //     400,000 B
  int*    next1    = (int*)(ws + 206127360);         //   1,200,000 B
  int*    next2    = (int*)(ws + 207327360);         //     600,000 B
  // total ws use: 207,927,360 B

  prep_scalars<<<1, 256, 0, stream>>>(b1a, bn1g, bn1b, bn1m, bn1v, b1b, gbrel,
                                      a1p, a2p, bng, bnb, bnm, bnv, fold1, c2, s2f);
  prep_w1<<<256, 256, 0, stream>>>(w1a, bn1g, bn1v, w1ab);
  prep_w2<<<256, 256, 0, stream>>>(w1b, wrel, wroot, a1p, a2p, bng, bnv, w2f);
  cast_x<<<12500, 256, 0, stream>>>(x, xbf);
  init_heads<<<391, 256, 0, stream>>>(head1, head2);
  build_lists<<<1172, 256, 0, stream>>>(ei, vi, head1, next1, head2, next2);
  aggregate<<<25000, 256, 0, stream>>>(xbf, epsp, ei, eattr, vi,
                                       head1, next1, head2, next2,
                                       aggr1_bf, aggr2_bf);
  gemm1<<<782, 512, 0, stream>>>(aggr1_bf, w1ab, fold1, t1);
  gemm2<<<782, 512, 0, stream>>>(t1, aggr2_bf, xbf, w2f, c2, s2f, (float*)d_out);
}